// Round 10
// baseline (222.705 us; speedup 1.0000x reference)
//
#include <hip/hip_runtime.h>
#include <hip/hip_bf16.h>

typedef __attribute__((ext_vector_type(8))) short short8;
typedef __attribute__((ext_vector_type(4))) float f32x4;
typedef __attribute__((ext_vector_type(16))) float f32x16;
typedef __attribute__((ext_vector_type(4))) unsigned short u16x4;

#define D_MODEL 1024
#define N_HEAD 16
#define HEAD_DIM 64
#define T_SEQ 2048
#define BATCH 2
#define M_TOK (BATCH * T_SEQ) /* 4096 */
#define QKV_STRIDE ((size_t)M_TOK * D_MODEL) /* elems per Q/K/V buffer */

__device__ __forceinline__ unsigned short f2bf(float f) {
    union { float f; unsigned u; } v; v.f = f;
    unsigned r = (v.u + 0x7fffu + ((v.u >> 16) & 1u)) >> 16;  // RNE
    return (unsigned short)r;
}

__device__ __forceinline__ float exp2_fast(float x) {
    float r;
    asm("v_exp_f32 %0, %1" : "=v"(r) : "v"(x));   // 2^x
    return r;
}

__device__ __forceinline__ void load16_lds(const unsigned short* g, unsigned short* l) {
    __builtin_amdgcn_global_load_lds(
        (const __attribute__((address_space(1))) unsigned int*)(g),
        (__attribute__((address_space(3))) unsigned int*)(l),
        16, 0, 0);
}

// ---------------- cast x (f32 -> bf16), vectorized ----------------
__global__ __launch_bounds__(256) void cast_x(const float* __restrict__ in,
                                              unsigned short* __restrict__ out, int n4) {
    int i = blockIdx.x * 256 + threadIdx.x;
    if (i < n4) {
        float4 v = ((const float4*)in)[i];
        u16x4 o;
        o.x = f2bf(v.x); o.y = f2bf(v.y); o.z = f2bf(v.z); o.w = f2bf(v.w);
        ((u16x4*)out)[i] = o;
    }
}

// ---------------- transpose + cast all 4 weights [1024][1024] f32 -> bf16 T ----------------
__global__ __launch_bounds__(256) void transpose_cast4(
    const float* __restrict__ w0, const float* __restrict__ w1,
    const float* __restrict__ w2, const float* __restrict__ w3,
    unsigned short* __restrict__ o0, unsigned short* __restrict__ o1,
    unsigned short* __restrict__ o2, unsigned short* __restrict__ o3)
{
    __shared__ float tile[32][33];
    const float* in; unsigned short* outT;
    switch (blockIdx.z) {
        case 0: in = w0; outT = o0; break;
        case 1: in = w1; outT = o1; break;
        case 2: in = w2; outT = o2; break;
        default: in = w3; outT = o3; break;
    }
    const int R = 1024, C = 1024;
    const int r0 = blockIdx.x * 32, c0 = blockIdx.y * 32;
    const int tx = threadIdx.x & 31, ty = threadIdx.x >> 5;  // ty 0..7
    #pragma unroll
    for (int jj = 0; jj < 32; jj += 8)
        tile[ty + jj][tx] = in[(size_t)(r0 + ty + jj) * C + c0 + tx];
    __syncthreads();
    #pragma unroll
    for (int jj = 0; jj < 32; jj += 8)
        outT[(size_t)(c0 + ty + jj) * R + r0 + tx] = f2bf(tile[tx][ty + jj]);
}

// ---------------- V transpose per head: [B,H,T,64] -> [B,H,64,T] ----------------
__global__ __launch_bounds__(256) void transpose_v(const unsigned short* __restrict__ in,
                                                   unsigned short* __restrict__ out) {
    __shared__ unsigned short tile[32][33];
    const int t0 = blockIdx.x * 32, d0 = blockIdx.y * 32, bh = blockIdx.z;
    const int tx = threadIdx.x & 31, ty = threadIdx.x >> 5;
    const unsigned short* ib = in + (size_t)bh * T_SEQ * HEAD_DIM;
    unsigned short* ob = out + (size_t)bh * HEAD_DIM * T_SEQ;
    #pragma unroll
    for (int jj = 0; jj < 32; jj += 8)
        tile[ty + jj][tx] = ib[(size_t)(t0 + ty + jj) * HEAD_DIM + d0 + tx];
    __syncthreads();
    #pragma unroll
    for (int jj = 0; jj < 32; jj += 8)
        ob[(size_t)(d0 + ty + jj) * T_SEQ + t0 + tx] = tile[tx][ty + jj];
}

// ---------------- 2-phase pipelined GEMM: C[M,N] = A[M,K] * Bt[N,K]^T ----------------
// BM=128, templated BN (128 or 64), BK=32, 4 waves, double-buffered LDS.
// mode 1: scatter into QKV: Q raw; K scaled by 0.125*log2(e); V raw [B,H,T,Dh]
// mode 2: f32 out[M,N] + bias[n]
#define BM 128
#define BK 32
template <int BNv>
__global__ __launch_bounds__(256) void gemm_bf16(
    const unsigned short* __restrict__ A,
    const unsigned short* __restrict__ Bt,
    void* __restrict__ outp,
    const float* __restrict__ bias,
    int M, int N, int K, int mode)
{
    constexpr int WN = BNv / 2;       // wave col extent
    constexpr int NJ = WN / 16;       // j-tiles per wave
    __shared__ unsigned short lds_a[2][BM * BK];
    __shared__ unsigned short lds_b[2][BNv * BK];
    const int tid = threadIdx.x;
    const int w = tid >> 6, l = tid & 63, lo = l & 15, hi = l >> 4;
    const int wm = w >> 1, wn = w & 1;
    const size_t arow0 = (size_t)blockIdx.x * BM;
    const size_t brow0 = (size_t)blockIdx.y * BNv;

    f32x4 acc[4][NJ];
    #pragma unroll
    for (int i = 0; i < 4; ++i)
        #pragma unroll
        for (int j = 0; j < NJ; ++j)
            acc[i][j] = (f32x4){0.f, 0.f, 0.f, 0.f};

    const int ch0 = tid, ch1 = 256 + tid;
    const int r0c = ch0 >> 2, c0c = (ch0 & 3) * 8;
    const int r1c = ch1 >> 2, c1c = (ch1 & 3) * 8;
    const unsigned short* Ab0 = A + (arow0 + r0c) * K + c0c;
    const unsigned short* Ab1 = A + (arow0 + r1c) * K + c1c;
    const unsigned short* Bb0 = Bt + (brow0 + r0c) * K + c0c;
    const unsigned short* Bb1 = Bt + (brow0 + r1c) * K + c1c;   // only used if BNv==128
    const int woff0 = (0 * 256 + w * 64) * 8, woff1 = (1 * 256 + w * 64) * 8;

#define GSTAGE(BUF, KOFF)                                        \
    do {                                                         \
        load16_lds(Ab0 + (KOFF), lds_a[BUF] + woff0);            \
        load16_lds(Ab1 + (KOFF), lds_a[BUF] + woff1);            \
        load16_lds(Bb0 + (KOFF), lds_b[BUF] + woff0);            \
        if constexpr (BNv == 128)                                \
            load16_lds(Bb1 + (KOFF), lds_b[BUF] + woff1);        \
    } while (0)

    GSTAGE(0, 0);
    int cur = 0;
    for (int k0 = 0; k0 < K; k0 += BK) {
        __syncthreads();                       // drains in-flight stage (vmcnt0) + barrier
        if (k0 + BK < K) GSTAGE(cur ^ 1, k0 + BK);   // overlap next stage with current MFMAs
        short8 af[4], bfr[NJ];
        #pragma unroll
        for (int i = 0; i < 4; ++i)
            af[i] = *(const short8*)(lds_a[cur] + (wm * 64 + i * 16 + lo) * BK + 8 * hi);
        #pragma unroll
        for (int j = 0; j < NJ; ++j)
            bfr[j] = *(const short8*)(lds_b[cur] + (wn * WN + j * 16 + lo) * BK + 8 * hi);
        #pragma unroll
        for (int i = 0; i < 4; ++i)
            #pragma unroll
            for (int j = 0; j < NJ; ++j)
                acc[i][j] = __builtin_amdgcn_mfma_f32_16x16x32_bf16(af[i], bfr[j], acc[i][j], 0, 0, 0);
        cur ^= 1;
    }
#undef GSTAGE

    const int m00 = (int)arow0 + wm * 64;
    const int n00 = (int)brow0 + wn * WN;
    if (mode == 1) {
        unsigned short* out = (unsigned short*)outp;
        #pragma unroll
        for (int i = 0; i < 4; ++i)
            #pragma unroll
            for (int j = 0; j < NJ; ++j) {
                const int nbase = n00 + j * 16;
                const int qkv = nbase >> 10;          // block-uniform (1024 % 128 == 0)
                #pragma unroll
                for (int e = 0; e < 4; ++e) {
                    const int m = m00 + i * 16 + 4 * hi + e;
                    const int n = nbase + lo;
                    const int b = m >> 11, t = m & 2047;
                    const int h = (n >> 6) & 15, d = n & 63;
                    const int bh = (b << 4) + h;
                    float v = acc[i][j][e];
                    if (qkv == 1) v *= 0.18033688f;   // 1/sqrt(Dh) * log2(e)
                    // Q, K, V all raw [B,H,T,Dh], section-selected by qkv
                    const size_t off = (size_t)qkv * QKV_STRIDE
                                     + ((size_t)bh * T_SEQ + t) * HEAD_DIM + d;
                    out[off] = f2bf(v);
                }
            }
    } else {
        float* out = (float*)outp;
        #pragma unroll
        for (int i = 0; i < 4; ++i)
            #pragma unroll
            for (int j = 0; j < NJ; ++j)
                #pragma unroll
                for (int e = 0; e < 4; ++e) {
                    const int m = m00 + i * 16 + 4 * hi + e;
                    const int n = n00 + j * 16 + lo;
                    out[(size_t)m * N + n] = acc[i][j][e] + bias[n];
                }
    }
}

// ---------------- causal flash attention: 4 waves x 32 q-rows, shared LDS K/V window ------
// Identical math/structure to R9 (verified); V^T now arrives via its own pointer.
__global__ __launch_bounds__(256) void attn_fwd(
    const unsigned short* __restrict__ QKV,   // Q | K(pre-scaled by 0.125*log2e) | (Vraw unused)
    const unsigned short* __restrict__ Vt,    // [B,H,Dh,T]
    unsigned short* __restrict__ ctx)
{
    const int qi = (int)(gridDim.x - 1 - blockIdx.x);  // longest-first, 0..15
    const int bh = blockIdx.y;
    const int b = bh >> 4, h = bh & 15;
    const int tid = threadIdx.x;
    const int wid = tid >> 6;
    const int l = tid & 63;
    const int l31 = l & 31, hi1 = l >> 5;
    const int q0w = qi * 128 + wid * 32;      // this wave's q-tile base
    const int q = q0w + l31;

    const unsigned short* Qb = QKV + (size_t)bh * T_SEQ * HEAD_DIM;
    const unsigned short* Kb = QKV + QKV_STRIDE + (size_t)bh * T_SEQ * HEAD_DIM;
    const unsigned short* Vb = Vt + (size_t)bh * HEAD_DIM * T_SEQ;

    __shared__ unsigned short kbuf[2][128 * 64];   // 2 x 16 KiB
    __shared__ unsigned short vbuf[2][64 * 128];   // 2 x 16 KiB

    short8 qf[4];
    #pragma unroll
    for (int st = 0; st < 4; ++st)
        qf[st] = *(const short8*)(Qb + (size_t)q * 64 + 16 * st + 8 * hi1);

    f32x16 o0, o1;
    #pragma unroll
    for (int r = 0; r < 16; ++r) { o0[r] = 0.f; o1[r] = 0.f; }
    float mrun = -3e38f, lsum = 0.f;

#define STAGE(B, SI)                                                                     \
    do {                                                                                 \
        _Pragma("unroll")                                                                \
        for (int it = 0; it < 4; ++it) {                                                 \
            const int D = it * 256 + tid;                                                \
            const int kr = D >> 3, kc = D & 7;                                           \
            load16_lds(Kb + (size_t)((SI) * 128 + kr) * 64 + ((kc ^ (kr & 7)) * 8),      \
                       &kbuf[B][(it * 256 + wid * 64) * 8]);                             \
            const int vr = D >> 4, vc = D & 15;                                          \
            load16_lds(Vb + (size_t)vr * T_SEQ + (SI) * 128 + ((vc ^ (vr & 7)) * 8),     \
                       &vbuf[B][(it * 256 + wid * 64) * 8]);                             \
        }                                                                                \
    } while (0)

    STAGE(0, 0);
    int cur = 0;
    for (int si = 0; si <= qi; ++si) {
        __syncthreads();                           // stage(si) done; prev buffer free
        if (si < qi) STAGE(cur ^ 1, si + 1);       // overlap with compute below
        #pragma unroll
        for (int kbl = 0; kbl < 4; ++kbl) {
            const int kbase = si * 128 + kbl * 32;
            if (kbase <= q0w) {
                short8 kf[4];
                #pragma unroll
                for (int st = 0; st < 4; ++st) {
                    const int r = kbl * 32 + l31;
                    const int cc = (2 * st + hi1) ^ (r & 7);
                    kf[st] = *(const short8*)&kbuf[cur][r * 64 + cc * 8];
                }
                f32x16 s_;
                #pragma unroll
                for (int r = 0; r < 16; ++r) s_[r] = 0.f;
                s_ = __builtin_amdgcn_mfma_f32_32x32x16_bf16(kf[0], qf[0], s_, 0, 0, 0);
                s_ = __builtin_amdgcn_mfma_f32_32x32x16_bf16(kf[1], qf[1], s_, 0, 0, 0);
                s_ = __builtin_amdgcn_mfma_f32_32x32x16_bf16(kf[2], qf[2], s_, 0, 0, 0);
                s_ = __builtin_amdgcn_mfma_f32_32x32x16_bf16(kf[3], qf[3], s_, 0, 0, 0);
                if (kbase == q0w) {   // diagonal block: mask k > q
                    #pragma unroll
                    for (int r = 0; r < 16; ++r)
                        if ((r & 3) + 8 * (r >> 2) + 4 * hi1 > l31) s_[r] = -3e38f;
                }
                float pm = s_[0];
                #pragma unroll
                for (int r = 1; r < 16; ++r) pm = fmaxf(pm, s_[r]);
                pm = fmaxf(pm, __shfl_xor(pm, 32));
                if (__any(pm > mrun + 8.0f)) {       // defer-max (T13)
                    const float mnew = fmaxf(mrun, pm);
                    const float sc = exp2_fast(mrun - mnew);
                    mrun = mnew;
                    lsum *= sc;
                    #pragma unroll
                    for (int r = 0; r < 16; ++r) { o0[r] *= sc; o1[r] *= sc; }
                }
                float p[16];
                #pragma unroll
                for (int r = 0; r < 16; ++r) p[r] = exp2_fast(s_[r] - mrun);
                float rs = (((p[0] + p[1]) + (p[2] + p[3])) + ((p[4] + p[5]) + (p[6] + p[7])))
                         + (((p[8] + p[9]) + (p[10] + p[11])) + ((p[12] + p[13]) + (p[14] + p[15])));
                rs += __shfl_xor(rs, 32);
                lsum += rs;
                unsigned c0, c1, c2, c3, c4, c5, c6, c7;
                asm volatile("v_cvt_pk_bf16_f32 %0, %1, %2" : "=v"(c0) : "v"(p[0]),  "v"(p[1]));
                asm volatile("v_cvt_pk_bf16_f32 %0, %1, %2" : "=v"(c1) : "v"(p[2]),  "v"(p[3]));
                asm volatile("v_cvt_pk_bf16_f32 %0, %1, %2" : "=v"(c2) : "v"(p[4]),  "v"(p[5]));
                asm volatile("v_cvt_pk_bf16_f32 %0, %1, %2" : "=v"(c3) : "v"(p[6]),  "v"(p[7]));
                asm volatile("v_cvt_pk_bf16_f32 %0, %1, %2" : "=v"(c4) : "v"(p[8]),  "v"(p[9]));
                asm volatile("v_cvt_pk_bf16_f32 %0, %1, %2" : "=v"(c5) : "v"(p[10]), "v"(p[11]));
                asm volatile("v_cvt_pk_bf16_f32 %0, %1, %2" : "=v"(c6) : "v"(p[12]), "v"(p[13]));
                asm volatile("v_cvt_pk_bf16_f32 %0, %1, %2" : "=v"(c7) : "v"(p[14]), "v"(p[15]));
                asm volatile("v_permlane32_swap_b32 %0, %1" : "+v"(c0), "+v"(c2));
                asm volatile("v_permlane32_swap_b32 %0, %1" : "+v"(c1), "+v"(c3));
                asm volatile("v_permlane32_swap_b32 %0, %1" : "+v"(c4), "+v"(c6));
                asm volatile("v_permlane32_swap_b32 %0, %1" : "+v"(c5), "+v"(c7));
                union { short8 v; unsigned u[4]; } pb0, pb1;
                pb0.u[0] = c0; pb0.u[1] = c1; pb0.u[2] = c2; pb0.u[3] = c3;
                pb1.u[0] = c4; pb1.u[1] = c5; pb1.u[2] = c6; pb1.u[3] = c7;
                const int d0 = l31, d1 = 32 + l31;
                const int cv00 = (kbl * 4 + 0 + hi1) ^ (d0 & 7);
                const int cv01 = (kbl * 4 + 2 + hi1) ^ (d0 & 7);
                const int cv10 = (kbl * 4 + 0 + hi1) ^ (d1 & 7);
                const int cv11 = (kbl * 4 + 2 + hi1) ^ (d1 & 7);
                const short8 v00 = *(const short8*)&vbuf[cur][d0 * 128 + cv00 * 8];
                const short8 v01 = *(const short8*)&vbuf[cur][d0 * 128 + cv01 * 8];
                const short8 v10 = *(const short8*)&vbuf[cur][d1 * 128 + cv10 * 8];
                const short8 v11 = *(const short8*)&vbuf[cur][d1 * 128 + cv11 * 8];
                o0 = __builtin_amdgcn_mfma_f32_32x32x16_bf16(v00, pb0.v, o0, 0, 0, 0);
                o0 = __builtin_amdgcn_mfma_f32_32x32x16_bf16(v01, pb1.v, o0, 0, 0, 0);
                o1 = __builtin_amdgcn_mfma_f32_32x32x16_bf16(v10, pb0.v, o1, 0, 0, 0);
                o1 = __builtin_amdgcn_mfma_f32_32x32x16_bf16(v11, pb1.v, o1, 0, 0, 0);
            }
        }
        cur ^= 1;
    }
#undef STAGE

    const float inv = 1.0f / lsum;
    unsigned short* crow = ctx + (size_t)(b * T_SEQ + q) * D_MODEL + h * 64;
    #pragma unroll
    for (int rq = 0; rq < 4; ++rq) {
        const int dd = 8 * rq + 4 * hi1;
        u16x4 ov;
        ov.x = f2bf(o0[4 * rq + 0] * inv);
        ov.y = f2bf(o0[4 * rq + 1] * inv);
        ov.z = f2bf(o0[4 * rq + 2] * inv);
        ov.w = f2bf(o0[4 * rq + 3] * inv);
        *(u16x4*)(crow + dd) = ov;
        u16x4 ov1;
        ov1.x = f2bf(o1[4 * rq + 0] * inv);
        ov1.y = f2bf(o1[4 * rq + 1] * inv);
        ov1.z = f2bf(o1[4 * rq + 2] * inv);
        ov1.w = f2bf(o1[4 * rq + 3] * inv);
        *(u16x4*)(crow + 32 + dd) = ov1;
    }
}

extern "C" void kernel_launch(void* const* d_in, const int* in_sizes, int n_in,
                              void* d_out, int out_size, void* d_ws, size_t ws_size,
                              hipStream_t stream)
{
    const float* x  = (const float*)d_in[0];
    const float* Wq = (const float*)d_in[1];
    const float* Wk = (const float*)d_in[2];
    const float* Wv = (const float*)d_in[3];
    const float* Wo = (const float*)d_in[4];
    const float* bo = (const float*)d_in[5];
    float* out = (float*)d_out;

    char* ws = (char*)d_ws;
    unsigned short* x_bf = (unsigned short*)(ws);                  // 8 MiB; dead after QKV GEMM
    unsigned short* WqT  = (unsigned short*)(ws + (8u << 20));     // 2 MiB
    unsigned short* WkT  = (unsigned short*)(ws + (10u << 20));    // 2 MiB
    unsigned short* WvT  = (unsigned short*)(ws + (12u << 20));    // 2 MiB
    unsigned short* WoT  = (unsigned short*)(ws + (14u << 20));    // 2 MiB
    unsigned short* QKV  = (unsigned short*)(ws + (16u << 20));    // 24 MiB: Q | K*scale | Vraw
    unsigned short* Vraw = (unsigned short*)(ws + (32u << 20));    // = QKV + 2*QKV_STRIDE
    unsigned short* Vt   = (unsigned short*)(ws);                  // 8 MiB, aliases dead x_bf
    unsigned short* ctx  = (unsigned short*)(ws + (40u << 20));    // 8 MiB
    (void)in_sizes; (void)n_in; (void)out_size; (void)ws_size;

    cast_x<<<dim3((M_TOK * D_MODEL / 4 + 255) / 256), 256, 0, stream>>>(x, x_bf, M_TOK * D_MODEL / 4);
    transpose_cast4<<<dim3(32, 32, 4), 256, 0, stream>>>(Wq, Wk, Wv, Wo, WqT, WkT, WvT, WoT);

    gemm_bf16<128><<<dim3(M_TOK / BM, 3072 / 128), 256, 0, stream>>>(
        x_bf, WqT, QKV, nullptr, M_TOK, 3072, D_MODEL, 1);

    transpose_v<<<dim3(T_SEQ / 32, HEAD_DIM / 32, BATCH * N_HEAD), 256, 0, stream>>>(Vraw, Vt);

    attn_fwd<<<dim3(T_SEQ / 128, BATCH * N_HEAD), 256, 0, stream>>>(QKV, Vt, ctx);

    gemm_bf16<64><<<dim3(M_TOK / BM, D_MODEL / 64), 256, 0, stream>>>(
        ctx, WoT, out, bo, M_TOK, D_MODEL, D_MODEL, 2);
}